// Round 1
// baseline (660.922 us; speedup 1.0000x reference)
//
#include <hip/hip_runtime.h>
#include <hip/hip_bf16.h>

#define N_NODES 20000
#define N_EDGES 150000
#define D 512
#define KK 3072          // 6 slots * 512
#define M_PAD 20096      // 157 * 128

typedef __attribute__((ext_vector_type(8))) short bf16x8_t;
typedef __attribute__((ext_vector_type(4))) float f32x4_t;

// ---- helpers ----
__device__ __forceinline__ unsigned short f2bf(float x) {
    unsigned u = __float_as_uint(x);
    unsigned r = u + 0x7fffu + ((u >> 16) & 1u);   // round-to-nearest-even
    return (unsigned short)(r >> 16);
}
__device__ __forceinline__ unsigned pack2(float a, float b) {
    return (unsigned)f2bf(a) | ((unsigned)f2bf(b) << 16);
}
__device__ __forceinline__ void atomic_pk_add_bf16(unsigned* addr, unsigned v) {
    asm volatile("global_atomic_pk_add_bf16 %0, %1, off" :: "v"(addr), "v"(v) : "memory");
}

#define GLOAD16(g, l)                                                                   \
    __builtin_amdgcn_global_load_lds(                                                   \
        (const __attribute__((address_space(1))) unsigned*)(g),                         \
        (__attribute__((address_space(3))) unsigned*)(l), 16, 0, 0)

// ---- B convert: Bt[e][k] = bf16(Wcat[k][e]), k = slot*512 + d ----
__global__ __launch_bounds__(256) void conv_B(const float* __restrict__ W_rel,
                                              const float* __restrict__ W_self,
                                              short* __restrict__ Bt) {
    int idx = blockIdx.x * 256 + threadIdx.x;      // 512*3072 threads
    int k = idx % KK;
    int e = idx / KK;
    int s = k >> 9, d = k & 511;
    float w = (s < 3) ? W_rel[((s << 9) + d) * D + e]
                      : W_self[(((s - 3) << 9) + d) * D + e];
    Bt[idx] = (short)f2bf(w);
}

// ---- self slot: A[n][(3+t)*512 + d] = bf16(x[n][d]) ----
__global__ __launch_bounds__(256) void self_copy(const float* __restrict__ x,
                                                 const int* __restrict__ ntype,
                                                 short* __restrict__ A) {
    int wid = threadIdx.x >> 6, lane = threadIdx.x & 63;
    int n = blockIdx.x * 4 + wid;
    if (n >= N_NODES) return;
    int t = ntype[n];
    const float4* xr = (const float4*)(x + (size_t)n * D);
    float4 v0 = xr[lane * 2];
    float4 v1 = xr[lane * 2 + 1];
    uint4 pk;
    pk.x = pack2(v0.x, v0.y); pk.y = pack2(v0.z, v0.w);
    pk.z = pack2(v1.x, v1.y); pk.w = pack2(v1.z, v1.w);
    *(uint4*)(A + (size_t)n * KK + (size_t)(3 + t) * D + lane * 8) = pk;
}

// ---- edge scatter: A[dst][r*512 + d] += bf16(x[src][d]) ; cnt[r][dst]++ ----
__global__ __launch_bounds__(256) void scatter_edges(const float* __restrict__ x,
                                                     const int* __restrict__ esrc,
                                                     const int* __restrict__ edst,
                                                     const int* __restrict__ etyp,
                                                     short* __restrict__ A,
                                                     int* __restrict__ cnt) {
    int wid = threadIdx.x >> 6, lane = threadIdx.x & 63;
    int e = blockIdx.x * 4 + wid;
    if (e >= N_EDGES) return;
    int src = esrc[e], dst = edst[e], r = etyp[e];
    if (lane == 0) atomicAdd(&cnt[r * N_NODES + dst], 1);
    const float4* xr = (const float4*)(x + (size_t)src * D);
    float4 v0 = xr[lane * 2];
    float4 v1 = xr[lane * 2 + 1];
    unsigned p0 = pack2(v0.x, v0.y), p1 = pack2(v0.z, v0.w);
    unsigned p2 = pack2(v1.x, v1.y), p3 = pack2(v1.z, v1.w);
    unsigned* base = (unsigned*)(A + (size_t)dst * KK + (size_t)r * D + lane * 8);
    atomic_pk_add_bf16(base + 0, p0);
    atomic_pk_add_bf16(base + 1, p1);
    atomic_pk_add_bf16(base + 2, p2);
    atomic_pk_add_bf16(base + 3, p3);
}

// ---- GEMM: out[m][c] = relu( sum_k A[m][k] Bt[c][k] + bias(m,c) ) ----
// m97-style 128x128 tile, 4 waves, 16x16x32 bf16 MFMA, global_load_lds width 16.
__global__ __launch_bounds__(256, 3) void gemm_bias_relu(
    const short* __restrict__ A, const short* __restrict__ Bt,
    float* __restrict__ out,
    const int* __restrict__ cnt, const float* __restrict__ b_rel,
    const float* __restrict__ b_self, const int* __restrict__ ntype) {
    __shared__ short lA[128 * 32];
    __shared__ short lB[128 * 32];
    const int tid = threadIdx.x;
    const int lane = tid & 63;
    const int wid = tid >> 6;
    const int wm = wid >> 1, wn = wid & 1;
    const int lr = lane & 15, lk = lane >> 4;

    const int tn = blockIdx.x;         // 0..3  (N tiles)
    const int tm = blockIdx.y;         // 0..156 (M tiles)
    const long arow0 = (long)tm * 128;
    const long brow0 = (long)tn * 128;

    f32x4_t acc[4][4] = {};

    for (int k0 = 0; k0 < KK; k0 += 32) {
#pragma unroll
        for (int rr = 0; rr < 2; ++rr) {
            int off = (rr * 256 + tid) * 16;       // byte offset in 8KB tile
            int row = off >> 6;                    // 64B per row (32 bf16)
            int cb = off & 63;
            const char* ga = (const char*)(A + (arow0 + row) * KK + k0) + cb;
            GLOAD16(ga, ((char*)lA) + off);
            const char* gb = (const char*)(Bt + (brow0 + row) * KK + k0) + cb;
            GLOAD16(gb, ((char*)lB) + off);
        }
        __syncthreads();
        bf16x8_t af[4], bfr[4];
#pragma unroll
        for (int m = 0; m < 4; ++m)
            af[m] = *(const bf16x8_t*)&lA[(wm * 64 + m * 16 + lr) * 32 + lk * 8];
#pragma unroll
        for (int n = 0; n < 4; ++n)
            bfr[n] = *(const bf16x8_t*)&lB[(wn * 64 + n * 16 + lr) * 32 + lk * 8];
#pragma unroll
        for (int m = 0; m < 4; ++m)
#pragma unroll
            for (int n = 0; n < 4; ++n)
                acc[m][n] = __builtin_amdgcn_mfma_f32_16x16x32_bf16(af[m], bfr[n], acc[m][n], 0, 0, 0);
        __syncthreads();
    }

#pragma unroll
    for (int m = 0; m < 4; ++m) {
#pragma unroll
        for (int q = 0; q < 4; ++q) {
            int rowg = tm * 128 + wm * 64 + m * 16 + lk * 4 + q;
            if (rowg >= N_NODES) continue;
            float c0 = (float)cnt[rowg];
            float c1 = (float)cnt[N_NODES + rowg];
            float c2 = (float)cnt[2 * N_NODES + rowg];
            int t = ntype[rowg];
#pragma unroll
            for (int n = 0; n < 4; ++n) {
                int colg = tn * 128 + wn * 64 + n * 16 + lr;
                float v = acc[m][n][q];
                v += c0 * b_rel[colg] + c1 * b_rel[D + colg] + c2 * b_rel[2 * D + colg];
                v += b_self[t * D + colg];
                v = v > 0.f ? v : 0.f;
                out[(long)rowg * D + colg] = v;
            }
        }
    }
}

extern "C" void kernel_launch(void* const* d_in, const int* in_sizes, int n_in,
                              void* d_out, int out_size, void* d_ws, size_t ws_size,
                              hipStream_t stream) {
    const float* x      = (const float*)d_in[0];
    const float* W_rel  = (const float*)d_in[1];
    const float* b_rel  = (const float*)d_in[2];
    const float* W_self = (const float*)d_in[3];
    const float* b_self = (const float*)d_in[4];
    const int* esrc     = (const int*)d_in[5];
    const int* edst     = (const int*)d_in[6];
    const int* etyp     = (const int*)d_in[7];
    const int* ntyp     = (const int*)d_in[8];
    float* out = (float*)d_out;

    char* ws = (char*)d_ws;
    const size_t A_BYTES   = (size_t)M_PAD * KK * 2;          // 123,469,824
    const size_t CNT_BYTES = (size_t)3 * N_NODES * 4;         // 240,000
    short* A   = (short*)ws;
    int*   cnt = (int*)(ws + A_BYTES);
    short* Bt  = (short*)(ws + A_BYTES + CNT_BYTES);          // 512*3072 bf16

    // zero A (padded) + cnt; Bt is fully overwritten
    hipMemsetAsync(ws, 0, A_BYTES + CNT_BYTES, stream);

    conv_B<<<(D * KK) / 256, 256, 0, stream>>>(W_rel, W_self, Bt);
    self_copy<<<N_NODES / 4, 256, 0, stream>>>(x, ntyp, A);
    scatter_edges<<<N_EDGES / 4, 256, 0, stream>>>(x, esrc, edst, etyp, A, cnt);
    gemm_bias_relu<<<dim3(4, 157), 256, 0, stream>>>(A, Bt, out, cnt, b_rel, b_self, ntyp);
}

// Round 2
// 237.806 us; speedup vs baseline: 2.7792x; 2.7792x over previous
//
#include <hip/hip_runtime.h>
#include <hip/hip_bf16.h>

#define N_NODES 20000
#define N_EDGES 150000
#define D 512
#define KK 3072          // 6 slots * 512
#define M_PAD 20096      // 157 * 128

typedef __attribute__((ext_vector_type(8))) short bf16x8_t;
typedef __attribute__((ext_vector_type(4))) float f32x4_t;

// ---- helpers ----
__device__ __forceinline__ unsigned short f2bf(float x) {
    unsigned u = __float_as_uint(x);
    unsigned r = u + 0x7fffu + ((u >> 16) & 1u);   // round-to-nearest-even
    return (unsigned short)(r >> 16);
}
__device__ __forceinline__ unsigned pack2(float a, float b) {
    return (unsigned)f2bf(a) | ((unsigned)f2bf(b) << 16);
}

#define GLOAD16(g, l)                                                                   \
    __builtin_amdgcn_global_load_lds(                                                   \
        (const __attribute__((address_space(1))) unsigned*)(g),                         \
        (__attribute__((address_space(3))) unsigned*)(l), 16, 0, 0)

// ---- B convert: Bt[e][k] = bf16(Wcat[k][e]), k = slot*512 + d ----
__global__ __launch_bounds__(256) void conv_B(const float* __restrict__ W_rel,
                                              const float* __restrict__ W_self,
                                              short* __restrict__ Bt) {
    int idx = blockIdx.x * 256 + threadIdx.x;      // 512*3072 threads
    int k = idx % KK;
    int e = idx / KK;
    int s = k >> 9, d = k & 511;
    float w = (s < 3) ? W_rel[((s << 9) + d) * D + e]
                      : W_self[(((s - 3) << 9) + d) * D + e];
    Bt[idx] = (short)f2bf(w);
}

// ---- histogram over dst ----
__global__ __launch_bounds__(256) void hist_k(const int* __restrict__ edst,
                                              int* __restrict__ hist) {
    int e = blockIdx.x * 256 + threadIdx.x;
    if (e < N_EDGES) atomicAdd(&hist[edst[e]], 1);
}

// ---- single-block exclusive scan of 20000 bins -> offs[20001], cur[20000] ----
__global__ __launch_bounds__(1024) void scan_k(const int* __restrict__ hist,
                                               int* __restrict__ offs,
                                               int* __restrict__ cur) {
    __shared__ int part[1024];
    const int t = threadIdx.x;
    const int base = t * 20;
    int local[20];
    int sum = 0;
#pragma unroll
    for (int i = 0; i < 20; ++i) {
        int b = base + i;
        int v = (b < N_NODES) ? hist[b] : 0;
        local[i] = sum;
        sum += v;
    }
    part[t] = sum;
    __syncthreads();
    for (int off = 1; off < 1024; off <<= 1) {
        int v = part[t];
        int u = (t >= off) ? part[t - off] : 0;
        __syncthreads();
        part[t] = v + u;
        __syncthreads();
    }
    int tbase = (t > 0) ? part[t - 1] : 0;
#pragma unroll
    for (int i = 0; i < 20; ++i) {
        int b = base + i;
        if (b < N_NODES) {
            int o = tbase + local[i];
            offs[b] = o;
            cur[b] = o;
        }
    }
    if (t == 1023) offs[N_NODES] = part[1023];
}

// ---- scatter edge ids into dst-sorted order; pack src | (rel<<16) ----
__global__ __launch_bounds__(256) void scatter_ids(const int* __restrict__ esrc,
                                                   const int* __restrict__ edst,
                                                   const int* __restrict__ etyp,
                                                   int* __restrict__ cur,
                                                   int* __restrict__ sorted) {
    int e = blockIdx.x * 256 + threadIdx.x;
    if (e >= N_EDGES) return;
    int dst = edst[e];
    int pos = atomicAdd(&cur[dst], 1);
    sorted[pos] = esrc[e] | (etyp[e] << 16);
}

// ---- aggregate: one wave per dst node; gather x[src] rows, accumulate in regs ----
__global__ __launch_bounds__(256) void aggregate(const float* __restrict__ x,
                                                 const int* __restrict__ offs,
                                                 const int* __restrict__ sorted,
                                                 const int* __restrict__ ntype,
                                                 short* __restrict__ A,
                                                 int* __restrict__ cnt) {
    const int wid = threadIdx.x >> 6, lane = threadIdx.x & 63;
    const int n = blockIdx.x * 4 + wid;
    if (n >= N_NODES) return;
    const int s = offs[n], e = offs[n + 1];
    const int m = e - s;

    float4 a0l = {0,0,0,0}, a0h = {0,0,0,0};
    float4 a1l = {0,0,0,0}, a1h = {0,0,0,0};
    float4 a2l = {0,0,0,0}, a2h = {0,0,0,0};
    int k0 = 0, k1 = 0, k2 = 0;

    // prefetch up to 64 packed edge descriptors into one VGPR, broadcast via shfl
    int pl = (lane < m) ? sorted[s + lane] : 0;
    const int mm = m < 64 ? m : 64;
    for (int i = 0; i < mm; ++i) {
        int p = __shfl(pl, i);
        int src = p & 0xffff;
        int r = p >> 16;
        const float4* xr = (const float4*)(x + (size_t)src * D) + lane * 2;
        float4 v0 = xr[0];
        float4 v1 = xr[1];
        if (r == 0) {
            a0l.x += v0.x; a0l.y += v0.y; a0l.z += v0.z; a0l.w += v0.w;
            a0h.x += v1.x; a0h.y += v1.y; a0h.z += v1.z; a0h.w += v1.w; k0++;
        } else if (r == 1) {
            a1l.x += v0.x; a1l.y += v0.y; a1l.z += v0.z; a1l.w += v0.w;
            a1h.x += v1.x; a1h.y += v1.y; a1h.z += v1.z; a1h.w += v1.w; k1++;
        } else {
            a2l.x += v0.x; a2l.y += v0.y; a2l.z += v0.z; a2l.w += v0.w;
            a2h.x += v1.x; a2h.y += v1.y; a2h.z += v1.z; a2h.w += v1.w; k2++;
        }
    }
    for (int i = 64; i < m; ++i) {        // overflow path (essentially never taken)
        int p = sorted[s + i];
        int src = p & 0xffff;
        int r = p >> 16;
        const float4* xr = (const float4*)(x + (size_t)src * D) + lane * 2;
        float4 v0 = xr[0];
        float4 v1 = xr[1];
        if (r == 0) {
            a0l.x += v0.x; a0l.y += v0.y; a0l.z += v0.z; a0l.w += v0.w;
            a0h.x += v1.x; a0h.y += v1.y; a0h.z += v1.z; a0h.w += v1.w; k0++;
        } else if (r == 1) {
            a1l.x += v0.x; a1l.y += v0.y; a1l.z += v0.z; a1l.w += v0.w;
            a1h.x += v1.x; a1h.y += v1.y; a1h.z += v1.z; a1h.w += v1.w; k1++;
        } else {
            a2l.x += v0.x; a2l.y += v0.y; a2l.z += v0.z; a2l.w += v0.w;
            a2h.x += v1.x; a2h.y += v1.y; a2h.z += v1.z; a2h.w += v1.w; k2++;
        }
    }

    short* row = A + (size_t)n * KK;
    uint4 q;
    q.x = pack2(a0l.x, a0l.y); q.y = pack2(a0l.z, a0l.w);
    q.z = pack2(a0h.x, a0h.y); q.w = pack2(a0h.z, a0h.w);
    *(uint4*)(row + 0 * D + lane * 8) = q;
    q.x = pack2(a1l.x, a1l.y); q.y = pack2(a1l.z, a1l.w);
    q.z = pack2(a1h.x, a1h.y); q.w = pack2(a1h.z, a1h.w);
    *(uint4*)(row + 1 * D + lane * 8) = q;
    q.x = pack2(a2l.x, a2l.y); q.y = pack2(a2l.z, a2l.w);
    q.z = pack2(a2h.x, a2h.y); q.w = pack2(a2h.z, a2h.w);
    *(uint4*)(row + 2 * D + lane * 8) = q;

    // self slots: zero except slot 3+t which carries x[n]
    const int t = ntype[n];
    const float4* xn = (const float4*)(x + (size_t)n * D) + lane * 2;
    float4 s0 = xn[0];
    float4 s1 = xn[1];
    uint4 px;
    px.x = pack2(s0.x, s0.y); px.y = pack2(s0.z, s0.w);
    px.z = pack2(s1.x, s1.y); px.w = pack2(s1.z, s1.w);
    uint4 zz = {0, 0, 0, 0};
#pragma unroll
    for (int ss = 0; ss < 3; ++ss)
        *(uint4*)(row + (3 + ss) * D + lane * 8) = (ss == t) ? px : zz;

    if (lane == 0) {
        cnt[n] = k0;
        cnt[N_NODES + n] = k1;
        cnt[2 * N_NODES + n] = k2;
    }
}

// ---- GEMM: out[m][c] = relu( sum_k A[m][k] Bt[c][k] + bias(m,c) ) ----
__global__ __launch_bounds__(256, 3) void gemm_bias_relu(
    const short* __restrict__ A, const short* __restrict__ Bt,
    float* __restrict__ out,
    const int* __restrict__ cnt, const float* __restrict__ b_rel,
    const float* __restrict__ b_self, const int* __restrict__ ntype) {
    __shared__ short lA[128 * 32];
    __shared__ short lB[128 * 32];
    const int tid = threadIdx.x;
    const int lane = tid & 63;
    const int wid = tid >> 6;
    const int wm = wid >> 1, wn = wid & 1;
    const int lr = lane & 15, lk = lane >> 4;

    const int tn = blockIdx.x;         // 0..3  (N tiles)
    const int tm = blockIdx.y;         // 0..156 (M tiles)
    const long arow0 = (long)tm * 128;
    const long brow0 = (long)tn * 128;

    f32x4_t acc[4][4] = {};

    for (int k0 = 0; k0 < KK; k0 += 32) {
#pragma unroll
        for (int rr = 0; rr < 2; ++rr) {
            int off = (rr * 256 + tid) * 16;       // byte offset in 8KB tile
            int row = off >> 6;                    // 64B per row (32 bf16)
            int cb = off & 63;
            const char* ga = (const char*)(A + (arow0 + row) * KK + k0) + cb;
            GLOAD16(ga, ((char*)lA) + off);
            const char* gb = (const char*)(Bt + (brow0 + row) * KK + k0) + cb;
            GLOAD16(gb, ((char*)lB) + off);
        }
        __syncthreads();
        bf16x8_t af[4], bfr[4];
#pragma unroll
        for (int m = 0; m < 4; ++m)
            af[m] = *(const bf16x8_t*)&lA[(wm * 64 + m * 16 + lr) * 32 + lk * 8];
#pragma unroll
        for (int n = 0; n < 4; ++n)
            bfr[n] = *(const bf16x8_t*)&lB[(wn * 64 + n * 16 + lr) * 32 + lk * 8];
#pragma unroll
        for (int m = 0; m < 4; ++m)
#pragma unroll
            for (int n = 0; n < 4; ++n)
                acc[m][n] = __builtin_amdgcn_mfma_f32_16x16x32_bf16(af[m], bfr[n], acc[m][n], 0, 0, 0);
        __syncthreads();
    }

#pragma unroll
    for (int m = 0; m < 4; ++m) {
#pragma unroll
        for (int q = 0; q < 4; ++q) {
            int rowg = tm * 128 + wm * 64 + m * 16 + lk * 4 + q;
            if (rowg >= N_NODES) continue;
            float c0 = (float)cnt[rowg];
            float c1 = (float)cnt[N_NODES + rowg];
            float c2 = (float)cnt[2 * N_NODES + rowg];
            int t = ntype[rowg];
#pragma unroll
            for (int n = 0; n < 4; ++n) {
                int colg = tn * 128 + wn * 64 + n * 16 + lr;
                float v = acc[m][n][q];
                v += c0 * b_rel[colg] + c1 * b_rel[D + colg] + c2 * b_rel[2 * D + colg];
                v += b_self[t * D + colg];
                v = v > 0.f ? v : 0.f;
                out[(long)rowg * D + colg] = v;
            }
        }
    }
}

extern "C" void kernel_launch(void* const* d_in, const int* in_sizes, int n_in,
                              void* d_out, int out_size, void* d_ws, size_t ws_size,
                              hipStream_t stream) {
    const float* x      = (const float*)d_in[0];
    const float* W_rel  = (const float*)d_in[1];
    const float* b_rel  = (const float*)d_in[2];
    const float* W_self = (const float*)d_in[3];
    const float* b_self = (const float*)d_in[4];
    const int* esrc     = (const int*)d_in[5];
    const int* edst     = (const int*)d_in[6];
    const int* etyp     = (const int*)d_in[7];
    const int* ntyp     = (const int*)d_in[8];
    float* out = (float*)d_out;

    char* ws = (char*)d_ws;
    const size_t A_BYTES    = (size_t)M_PAD * KK * 2;          // 123,469,824
    const size_t BT_BYTES   = (size_t)D * KK * 2;              // 3,145,728
    const size_t CNT_BYTES  = (size_t)3 * N_NODES * 4;         // 240,000
    const size_t OFFS_BYTES = (size_t)(N_NODES + 4) * 4;       // 80,016
    const size_t CUR_BYTES  = (size_t)N_NODES * 4;             // 80,000
    const size_t HIST_BYTES = (size_t)N_NODES * 4;             // 80,000

    size_t o = 0;
    short* A      = (short*)(ws + o); o += A_BYTES;
    short* Bt     = (short*)(ws + o); o += BT_BYTES;
    int*   cnt    = (int*)(ws + o);   o += CNT_BYTES;
    int*   offs   = (int*)(ws + o);   o += OFFS_BYTES;
    int*   cur    = (int*)(ws + o);   o += CUR_BYTES;
    int*   hist   = (int*)(ws + o);   o += HIST_BYTES;
    int*   sorted = (int*)(ws + o);   // 600,000 bytes

    hipMemsetAsync(hist, 0, HIST_BYTES, stream);

    conv_B<<<(D * KK) / 256, 256, 0, stream>>>(W_rel, W_self, Bt);
    hist_k<<<(N_EDGES + 255) / 256, 256, 0, stream>>>(edst, hist);
    scan_k<<<1, 1024, 0, stream>>>(hist, offs, cur);
    scatter_ids<<<(N_EDGES + 255) / 256, 256, 0, stream>>>(esrc, edst, etyp, cur, sorted);
    aggregate<<<(N_NODES + 3) / 4, 256, 0, stream>>>(x, offs, sorted, ntyp, A, cnt);
    gemm_bias_relu<<<dim3(4, 157), 256, 0, stream>>>(A, Bt, out, cnt, b_rel, b_self, ntyp);
}

// Round 3
// 192.943 us; speedup vs baseline: 3.4255x; 1.2325x over previous
//
#include <hip/hip_runtime.h>
#include <hip/hip_bf16.h>

#define N_NODES 20000
#define N_EDGES 150000
#define D 512
#define KK 2048          // 3 rel slots + 1 self slot
#define KREL 1536
#define NROWS 20480      // 160 tiles * 128
#define NTILES_M 160

typedef __attribute__((ext_vector_type(8))) short bf16x8_t;
typedef __attribute__((ext_vector_type(4))) float f32x4_t;

// ---- helpers ----
__device__ __forceinline__ unsigned short f2bf(float x) {
    unsigned u = __float_as_uint(x);
    unsigned r = u + 0x7fffu + ((u >> 16) & 1u);   // RNE
    return (unsigned short)(r >> 16);
}
__device__ __forceinline__ unsigned pack2(float a, float b) {
    return (unsigned)f2bf(a) | ((unsigned)f2bf(b) << 16);
}
__device__ __forceinline__ float bflo(unsigned u) { return __uint_as_float(u << 16); }
__device__ __forceinline__ float bfhi(unsigned u) { return __uint_as_float(u & 0xffff0000u); }

#define GLOAD16(g, l)                                                                   \
    __builtin_amdgcn_global_load_lds(                                                   \
        (const __attribute__((address_space(1))) unsigned*)(g),                         \
        (__attribute__((address_space(3))) unsigned*)(l), 16, 0, 0)

// ---- Bt[e][k] (row stride 3072): k<1536 = W_rel^T, 1536+t*512+d = W_self[t]^T ----
__global__ __launch_bounds__(256) void transpose_B(const float* __restrict__ W_rel,
                                                   const float* __restrict__ W_self,
                                                   short* __restrict__ Bt) {
    __shared__ float tile[64][65];
    const int z = blockIdx.z;                       // 0..5
    const float* src = (z < 3) ? (W_rel + (size_t)z * D * D)
                               : (W_self + (size_t)(z - 3) * D * D);
    const int cbase = (z < 3) ? z * 512 : KREL + (z - 3) * 512;
    const int e0 = blockIdx.x * 64, d0 = blockIdx.y * 64;
    const int tx = threadIdx.x & 63, ty = threadIdx.x >> 6;
#pragma unroll
    for (int j = 0; j < 16; ++j) {
        int dl = ty * 16 + j;
        tile[dl][tx] = src[(size_t)(d0 + dl) * D + e0 + tx];
    }
    __syncthreads();
#pragma unroll
    for (int j = 0; j < 16; ++j) {
        int el = ty * 16 + j;
        Bt[(size_t)(e0 + el) * 3072 + cbase + d0 + tx] = (short)f2bf(tile[tx][el]);
    }
}

// ---- x -> bf16 ----
__global__ __launch_bounds__(256) void conv_x(const float* __restrict__ x,
                                              short* __restrict__ xb) {
    int idx = blockIdx.x * 256 + threadIdx.x;       // 1,280,000 threads, 8 elems each
    const float4* s = (const float4*)x + (size_t)idx * 2;
    float4 a = s[0], b = s[1];
    uint4 pk;
    pk.x = pack2(a.x, a.y); pk.y = pack2(a.z, a.w);
    pk.z = pack2(b.x, b.y); pk.w = pack2(b.z, b.w);
    ((uint4*)xb)[idx] = pk;
}

// ---- histogram over dst ----
__global__ __launch_bounds__(256) void hist_k(const int* __restrict__ edst,
                                              int* __restrict__ hist) {
    int e = blockIdx.x * 256 + threadIdx.x;
    if (e < N_EDGES) atomicAdd(&hist[edst[e]], 1);
}

// ---- node-type counts (wave-aggregated) ----
__global__ __launch_bounds__(256) void typecnt_k(const int* __restrict__ ntype,
                                                 int* __restrict__ tcnt) {
    int n = blockIdx.x * 256 + threadIdx.x;
    int lane = threadIdx.x & 63;
    int t = (n < N_NODES) ? ntype[n] : 3;
    unsigned long long m0 = __ballot(t == 0), m1 = __ballot(t == 1), m2 = __ballot(t == 2);
    if (lane == 0) {
        if (m0) atomicAdd(&tcnt[0], __popcll(m0));
        if (m1) atomicAdd(&tcnt[1], __popcll(m1));
        if (m2) atomicAdd(&tcnt[2], __popcll(m2));
    }
}

// ---- scan of 20000 edge-bins -> offs/cur; thread 0 also builds padded type offsets ----
__global__ __launch_bounds__(1024) void scan_k(const int* __restrict__ hist,
                                               int* __restrict__ offs,
                                               int* __restrict__ cur,
                                               const int* __restrict__ tcnt,
                                               int* __restrict__ typeoff) {
    __shared__ int part[1024];
    const int t = threadIdx.x;
    const int base = t * 20;
    int local[20];
    int sum = 0;
#pragma unroll
    for (int i = 0; i < 20; ++i) {
        int b = base + i;
        int v = (b < N_NODES) ? hist[b] : 0;
        local[i] = sum;
        sum += v;
    }
    part[t] = sum;
    __syncthreads();
    for (int off = 1; off < 1024; off <<= 1) {
        int v = part[t];
        int u = (t >= off) ? part[t - off] : 0;
        __syncthreads();
        part[t] = v + u;
        __syncthreads();
    }
    int tbase = (t > 0) ? part[t - 1] : 0;
#pragma unroll
    for (int i = 0; i < 20; ++i) {
        int b = base + i;
        if (b < N_NODES) {
            int o = tbase + local[i];
            offs[b] = o;
            cur[b] = o;
        }
    }
    if (t == 1023) offs[N_NODES] = part[1023];
    if (t == 0) {
        int o1 = (tcnt[0] + 127) & ~127;
        int o2 = o1 + ((tcnt[1] + 127) & ~127);
        int o3 = o2 + ((tcnt[2] + 127) & ~127);
        typeoff[0] = 0; typeoff[1] = o1; typeoff[2] = o2; typeoff[3] = o3;
    }
}

// ---- assign node -> row (grouped by type), build rowmap ----
__global__ __launch_bounds__(256) void assign_k(const int* __restrict__ ntype,
                                                const int* __restrict__ typeoff,
                                                int* __restrict__ tcur,
                                                int* __restrict__ noderow,
                                                int* __restrict__ rowmap) {
    int n = blockIdx.x * 256 + threadIdx.x;
    int lane = threadIdx.x & 63;
    bool valid = n < N_NODES;
    int t = valid ? ntype[n] : 3;
    unsigned long long m0 = __ballot(t == 0), m1 = __ballot(t == 1), m2 = __ballot(t == 2);
    unsigned long long below = (lane == 0) ? 0ull : (~0ull >> (64 - lane));
    int b0 = 0, b1 = 0, b2 = 0;
    if (lane == 0) {
        if (m0) b0 = atomicAdd(&tcur[0], __popcll(m0));
        if (m1) b1 = atomicAdd(&tcur[1], __popcll(m1));
        if (m2) b2 = atomicAdd(&tcur[2], __popcll(m2));
    }
    b0 = __shfl(b0, 0); b1 = __shfl(b1, 0); b2 = __shfl(b2, 0);
    if (valid) {
        unsigned long long mk = (t == 0) ? m0 : (t == 1) ? m1 : m2;
        int bs = (t == 0) ? b0 : (t == 1) ? b1 : b2;
        int row = typeoff[t] + bs + __popcll(mk & below);
        noderow[n] = row;
        rowmap[row] = n;
    }
}

// ---- scatter edge ids into dst-sorted order; pack src | (rel<<16) ----
__global__ __launch_bounds__(256) void scatter_ids(const int* __restrict__ esrc,
                                                   const int* __restrict__ edst,
                                                   const int* __restrict__ etyp,
                                                   int* __restrict__ cur,
                                                   int* __restrict__ sorted) {
    int e = blockIdx.x * 256 + threadIdx.x;
    if (e >= N_EDGES) return;
    int dst = edst[e];
    int pos = atomicAdd(&cur[dst], 1);
    sorted[pos] = esrc[e] | (etyp[e] << 16);
}

// ---- aggregate: one wave per dst node; gather bf16 x rows, fp32 accum in regs ----
__global__ __launch_bounds__(256) void aggregate(const short* __restrict__ xb,
                                                 const int* __restrict__ offs,
                                                 const int* __restrict__ sorted,
                                                 const int* __restrict__ noderow,
                                                 short* __restrict__ A,
                                                 int* __restrict__ cnt) {
    const int wid = threadIdx.x >> 6, lane = threadIdx.x & 63;
    const int n = blockIdx.x * 4 + wid;
    if (n >= N_NODES) return;
    const int s = offs[n], e = offs[n + 1];
    const int m = e - s;

    float a00=0,a01=0,a02=0,a03=0,a04=0,a05=0,a06=0,a07=0;
    float a10=0,a11=0,a12=0,a13=0,a14=0,a15=0,a16=0,a17=0;
    float a20=0,a21=0,a22=0,a23=0,a24=0,a25=0,a26=0,a27=0;
    int k0 = 0, k1 = 0, k2 = 0;

    int pl = (lane < m) ? sorted[s + lane] : 0;
    const int mm = m < 64 ? m : 64;
    for (int i = 0; i < mm; ++i) {
        int p = __shfl(pl, i);
        int src = p & 0xffff;
        int r = p >> 16;
        uint4 v = ((const uint4*)(xb + (size_t)src * D))[lane];
        float f0 = bflo(v.x), f1 = bfhi(v.x), f2 = bflo(v.y), f3 = bfhi(v.y);
        float f4 = bflo(v.z), f5 = bfhi(v.z), f6 = bflo(v.w), f7 = bfhi(v.w);
        if (r == 0) { a00+=f0;a01+=f1;a02+=f2;a03+=f3;a04+=f4;a05+=f5;a06+=f6;a07+=f7; k0++; }
        else if (r == 1) { a10+=f0;a11+=f1;a12+=f2;a13+=f3;a14+=f4;a15+=f5;a16+=f6;a17+=f7; k1++; }
        else { a20+=f0;a21+=f1;a22+=f2;a23+=f3;a24+=f4;a25+=f5;a26+=f6;a27+=f7; k2++; }
    }
    for (int i = 64; i < m; ++i) {       // overflow path (essentially never taken)
        int p = sorted[s + i];
        int src = p & 0xffff;
        int r = p >> 16;
        uint4 v = ((const uint4*)(xb + (size_t)src * D))[lane];
        float f0 = bflo(v.x), f1 = bfhi(v.x), f2 = bflo(v.y), f3 = bfhi(v.y);
        float f4 = bflo(v.z), f5 = bfhi(v.z), f6 = bflo(v.w), f7 = bfhi(v.w);
        if (r == 0) { a00+=f0;a01+=f1;a02+=f2;a03+=f3;a04+=f4;a05+=f5;a06+=f6;a07+=f7; k0++; }
        else if (r == 1) { a10+=f0;a11+=f1;a12+=f2;a13+=f3;a14+=f4;a15+=f5;a16+=f6;a17+=f7; k1++; }
        else { a20+=f0;a21+=f1;a22+=f2;a23+=f3;a24+=f4;a25+=f5;a26+=f6;a27+=f7; k2++; }
    }

    const int rowid = noderow[n];
    short* row = A + (size_t)rowid * KK;
    uint4 q;
    q.x = pack2(a00, a01); q.y = pack2(a02, a03); q.z = pack2(a04, a05); q.w = pack2(a06, a07);
    *(uint4*)(row + 0 * D + lane * 8) = q;
    q.x = pack2(a10, a11); q.y = pack2(a12, a13); q.z = pack2(a14, a15); q.w = pack2(a16, a17);
    *(uint4*)(row + 1 * D + lane * 8) = q;
    q.x = pack2(a20, a21); q.y = pack2(a22, a23); q.z = pack2(a24, a25); q.w = pack2(a26, a27);
    *(uint4*)(row + 2 * D + lane * 8) = q;
    // self slot = xb[n]
    *(uint4*)(row + 3 * D + lane * 8) = ((const uint4*)(xb + (size_t)n * D))[lane];

    if (lane == 0) {
        cnt[n] = k0;
        cnt[N_NODES + n] = k1;
        cnt[2 * N_NODES + n] = k2;
    }
}

// ---- GEMM with swizzled staging (conflict-free LDS) + XCD-chunked block map ----
__global__ __launch_bounds__(256, 3) void gemm_bias_relu(
    const short* __restrict__ A, const short* __restrict__ Bt,
    float* __restrict__ out,
    const int* __restrict__ cnt, const float* __restrict__ b_rel,
    const float* __restrict__ b_self, const int* __restrict__ typeoff,
    const int* __restrict__ rowmap) {
    __shared__ short lA[4096];
    __shared__ short lB[4096];
    const int tid = threadIdx.x;
    const int lane = tid & 63;
    const int wid = tid >> 6;
    const int wm = wid >> 1, wn = wid & 1;
    const int lr = lane & 15, lk = lane >> 4;

    // bijective XCD-chunk swizzle: 640 blocks, 8 XCDs, 80/XCD; tn-siblings adjacent
    const int lin = blockIdx.x;
    const int mapped = (lin & 7) * 80 + (lin >> 3);
    const int tm = mapped >> 2;
    const int tn = mapped & 3;

    const int o1 = typeoff[1], o2 = typeoff[2], Mtot = typeoff[3];
    const int arow0 = tm * 128;
    if (arow0 >= Mtot) return;
    const int ttile = (arow0 >= o2) ? 2 : (arow0 >= o1) ? 1 : 0;
    const int tsel = ttile * 512;
    const int brow0 = tn * 128;

    f32x4_t acc[4][4] = {};

    for (int k0 = 0; k0 < KK; k0 += 32) {
        const int bk0 = k0 + (k0 >= KREL ? tsel : 0);
#pragma unroll
        for (int rr = 0; rr < 2; ++rr) {
            int p = rr * 256 + tid;                   // 16B-fragment index 0..511
            int row = p >> 2;
            int kg = (p & 3) ^ ((row >> 1) & 3);      // source-side swizzle
            const short* ga = A + (size_t)(arow0 + row) * KK + k0 + kg * 8;
            GLOAD16(ga, ((char*)lA) + p * 16);
            const short* gb = Bt + (size_t)(brow0 + row) * 3072 + bk0 + kg * 8;
            GLOAD16(gb, ((char*)lB) + p * 16);
        }
        __syncthreads();
        bf16x8_t af[4], bfr[4];
#pragma unroll
        for (int m = 0; m < 4; ++m) {
            int row_l = wm * 64 + m * 16 + lr;
            int pos = row_l * 4 + (lk ^ ((row_l >> 1) & 3));
            af[m] = *(const bf16x8_t*)&lA[pos * 8];
        }
#pragma unroll
        for (int n = 0; n < 4; ++n) {
            int row_l = wn * 64 + n * 16 + lr;
            int pos = row_l * 4 + (lk ^ ((row_l >> 1) & 3));
            bfr[n] = *(const bf16x8_t*)&lB[pos * 8];
        }
#pragma unroll
        for (int m = 0; m < 4; ++m)
#pragma unroll
            for (int n = 0; n < 4; ++n)
                acc[m][n] = __builtin_amdgcn_mfma_f32_16x16x32_bf16(af[m], bfr[n], acc[m][n], 0, 0, 0);
        __syncthreads();
    }

#pragma unroll
    for (int m = 0; m < 4; ++m) {
#pragma unroll
        for (int q = 0; q < 4; ++q) {
            int rowg = arow0 + wm * 64 + m * 16 + lk * 4 + q;
            int node = rowmap[rowg];
            if (node < 0) continue;
            float c0 = (float)cnt[node];
            float c1 = (float)cnt[N_NODES + node];
            float c2 = (float)cnt[2 * N_NODES + node];
#pragma unroll
            for (int n = 0; n < 4; ++n) {
                int colg = tn * 128 + wn * 64 + n * 16 + lr;
                float v = acc[m][n][q];
                v += c0 * b_rel[colg] + c1 * b_rel[D + colg] + c2 * b_rel[2 * D + colg];
                v += b_self[tsel + colg];
                v = v > 0.f ? v : 0.f;
                out[(size_t)node * D + colg] = v;
            }
        }
    }
}

extern "C" void kernel_launch(void* const* d_in, const int* in_sizes, int n_in,
                              void* d_out, int out_size, void* d_ws, size_t ws_size,
                              hipStream_t stream) {
    const float* x      = (const float*)d_in[0];
    const float* W_rel  = (const float*)d_in[1];
    const float* b_rel  = (const float*)d_in[2];
    const float* W_self = (const float*)d_in[3];
    const float* b_self = (const float*)d_in[4];
    const int* esrc     = (const int*)d_in[5];
    const int* edst     = (const int*)d_in[6];
    const int* etyp     = (const int*)d_in[7];
    const int* ntyp     = (const int*)d_in[8];
    float* out = (float*)d_out;

    char* ws = (char*)d_ws;
    size_t o = 0;
    short* A       = (short*)(ws + o); o += (size_t)NROWS * KK * 2;      // 83,886,080
    short* Bt      = (short*)(ws + o); o += (size_t)D * 3072 * 2;        // 3,145,728
    short* xb      = (short*)(ws + o); o += (size_t)N_NODES * D * 2;     // 20,480,000
    int*   cnt     = (int*)(ws + o);   o += (size_t)3 * N_NODES * 4;     // 240,000
    int*   offs    = (int*)(ws + o);   o += 80032;
    int*   cur     = (int*)(ws + o);   o += 80000;
    int*   noderow = (int*)(ws + o);   o += 80000;
    int*   rowmap  = (int*)(ws + o);   o += (size_t)NROWS * 4;           // 81,920
    int*   sorted  = (int*)(ws + o);   o += 600000;
    // zero-region: hist + tcnt + tcur + typeoff (contiguous)
    int*   hist    = (int*)(ws + o);   o += 80000;
    int*   tcnt    = (int*)(ws + o);   o += 16;
    int*   tcur    = (int*)(ws + o);   o += 16;
    int*   typeoff = (int*)(ws + o);   o += 16;

    hipMemsetAsync(hist, 0, 80032, stream);
    hipMemsetAsync(rowmap, 0xFF, (size_t)NROWS * 4, stream);

    transpose_B<<<dim3(8, 8, 6), 256, 0, stream>>>(W_rel, W_self, Bt);
    conv_x<<<(N_NODES * D / 8) / 256, 256, 0, stream>>>(x, xb);
    hist_k<<<(N_EDGES + 255) / 256, 256, 0, stream>>>(edst, hist);
    typecnt_k<<<(N_NODES + 255) / 256, 256, 0, stream>>>(ntyp, tcnt);
    scan_k<<<1, 1024, 0, stream>>>(hist, offs, cur, tcnt, typeoff);
    assign_k<<<(N_NODES + 255) / 256, 256, 0, stream>>>(ntyp, typeoff, tcur, noderow, rowmap);
    scatter_ids<<<(N_EDGES + 255) / 256, 256, 0, stream>>>(esrc, edst, etyp, cur, sorted);
    aggregate<<<(N_NODES + 3) / 4, 256, 0, stream>>>(xb, offs, sorted, noderow, A, cnt);
    gemm_bias_relu<<<NTILES_M * 4, 256, 0, stream>>>(A, Bt, out, cnt, b_rel, b_self,
                                                     typeoff, rowmap);
}

// Round 4
// 170.656 us; speedup vs baseline: 3.8728x; 1.1306x over previous
//
#include <hip/hip_runtime.h>
#include <hip/hip_bf16.h>

#define N_NODES 20000
#define N_EDGES 150000
#define D 512
#define KK 2048          // 3 rel slots + 1 self slot
#define KREL 1536
#define NROWS 20480      // 160 tiles * 128
#define NTILES_M 160

typedef __attribute__((ext_vector_type(8))) short bf16x8_t;
typedef __attribute__((ext_vector_type(4))) float f32x4_t;

// ---- helpers ----
__device__ __forceinline__ unsigned short f2bf(float x) {
    unsigned u = __float_as_uint(x);
    unsigned r = u + 0x7fffu + ((u >> 16) & 1u);   // RNE
    return (unsigned short)(r >> 16);
}
__device__ __forceinline__ unsigned pack2(float a, float b) {
    return (unsigned)f2bf(a) | ((unsigned)f2bf(b) << 16);
}
__device__ __forceinline__ float bflo(unsigned u) { return __uint_as_float(u << 16); }
__device__ __forceinline__ float bfhi(unsigned u) { return __uint_as_float(u & 0xffff0000u); }

#define GLOAD16(g, l)                                                                   \
    __builtin_amdgcn_global_load_lds(                                                   \
        (const __attribute__((address_space(1))) unsigned*)(g),                         \
        (__attribute__((address_space(3))) unsigned*)(l), 16, 0, 0)

// ---- Bt[e][k] (row stride 3072): k<1536 = W_rel^T, 1536+t*512+d = W_self[t]^T ----
__global__ __launch_bounds__(256) void transpose_B(const float* __restrict__ W_rel,
                                                   const float* __restrict__ W_self,
                                                   short* __restrict__ Bt) {
    __shared__ float tile[64][65];
    const int z = blockIdx.z;                       // 0..5
    const float* src = (z < 3) ? (W_rel + (size_t)z * D * D)
                               : (W_self + (size_t)(z - 3) * D * D);
    const int cbase = (z < 3) ? z * 512 : KREL + (z - 3) * 512;
    const int e0 = blockIdx.x * 64, d0 = blockIdx.y * 64;
    const int tx = threadIdx.x & 63, ty = threadIdx.x >> 6;
#pragma unroll
    for (int j = 0; j < 16; ++j) {
        int dl = ty * 16 + j;
        tile[dl][tx] = src[(size_t)(d0 + dl) * D + e0 + tx];
    }
    __syncthreads();
#pragma unroll
    for (int j = 0; j < 16; ++j) {
        int el = ty * 16 + j;
        Bt[(size_t)(e0 + el) * 3072 + cbase + d0 + tx] = (short)f2bf(tile[tx][el]);
    }
}

// ---- x -> bf16; also zero hist/tcnt/tcur/typeoff region and init rowmap = -1 ----
__global__ __launch_bounds__(256) void conv_x(const float* __restrict__ x,
                                              short* __restrict__ xb,
                                              int* __restrict__ zbase,
                                              int* __restrict__ rowmap) {
    int idx = blockIdx.x * 256 + threadIdx.x;       // 1,280,000 threads, 8 elems each
    if (idx < 20012) zbase[idx] = 0;                // hist[20000] + tcnt[4] + tcur[4] + typeoff[4]
    if (idx < NROWS) rowmap[idx] = -1;
    const float4* s = (const float4*)x + (size_t)idx * 2;
    float4 a = s[0], b = s[1];
    uint4 pk;
    pk.x = pack2(a.x, a.y); pk.y = pack2(a.z, a.w);
    pk.z = pack2(b.x, b.y); pk.w = pack2(b.z, b.w);
    ((uint4*)xb)[idx] = pk;
}

// ---- edge-dst histogram + node-type counts (fused) ----
__global__ __launch_bounds__(256) void count_k(const int* __restrict__ edst,
                                               int* __restrict__ hist,
                                               const int* __restrict__ ntype,
                                               int* __restrict__ tcnt) {
    int i = blockIdx.x * 256 + threadIdx.x;
    if (i < N_EDGES) atomicAdd(&hist[edst[i]], 1);
    int lane = threadIdx.x & 63;
    int t = (i < N_NODES) ? ntype[i] : 3;
    unsigned long long m0 = __ballot(t == 0), m1 = __ballot(t == 1), m2 = __ballot(t == 2);
    if (lane == 0) {
        if (m0) atomicAdd(&tcnt[0], __popcll(m0));
        if (m1) atomicAdd(&tcnt[1], __popcll(m1));
        if (m2) atomicAdd(&tcnt[2], __popcll(m2));
    }
}

// ---- scan of 20000 edge-bins -> offs/cur; thread 0 builds padded type offsets ----
__global__ __launch_bounds__(1024) void scan_k(const int* __restrict__ hist,
                                               int* __restrict__ offs,
                                               int* __restrict__ cur,
                                               const int* __restrict__ tcnt,
                                               int* __restrict__ typeoff) {
    __shared__ int part[1024];
    const int t = threadIdx.x;
    const int base = t * 20;
    int local[20];
    int sum = 0;
#pragma unroll
    for (int i = 0; i < 20; ++i) {
        int b = base + i;
        int v = (b < N_NODES) ? hist[b] : 0;
        local[i] = sum;
        sum += v;
    }
    part[t] = sum;
    __syncthreads();
    for (int off = 1; off < 1024; off <<= 1) {
        int v = part[t];
        int u = (t >= off) ? part[t - off] : 0;
        __syncthreads();
        part[t] = v + u;
        __syncthreads();
    }
    int tbase = (t > 0) ? part[t - 1] : 0;
#pragma unroll
    for (int i = 0; i < 20; ++i) {
        int b = base + i;
        if (b < N_NODES) {
            int o = tbase + local[i];
            offs[b] = o;
            cur[b] = o;
        }
    }
    if (t == 1023) offs[N_NODES] = part[1023];
    if (t == 0) {
        int o1 = (tcnt[0] + 127) & ~127;
        int o2 = o1 + ((tcnt[1] + 127) & ~127);
        int o3 = o2 + ((tcnt[2] + 127) & ~127);
        typeoff[0] = 0; typeoff[1] = o1; typeoff[2] = o2; typeoff[3] = o3;
    }
}

// ---- node->row assignment (type-grouped) + edge-id scatter (fused) ----
__global__ __launch_bounds__(256) void assign_scatter_k(
    const int* __restrict__ ntype, const int* __restrict__ typeoff,
    int* __restrict__ tcur, int* __restrict__ noderow, int* __restrict__ rowmap,
    const int* __restrict__ esrc, const int* __restrict__ edst,
    const int* __restrict__ etyp, int* __restrict__ cur, int* __restrict__ sorted) {
    int i = blockIdx.x * 256 + threadIdx.x;
    int lane = threadIdx.x & 63;
    bool valid = i < N_NODES;
    int t = valid ? ntype[i] : 3;
    unsigned long long m0 = __ballot(t == 0), m1 = __ballot(t == 1), m2 = __ballot(t == 2);
    unsigned long long below = (lane == 0) ? 0ull : (~0ull >> (64 - lane));
    int b0 = 0, b1 = 0, b2 = 0;
    if (lane == 0) {
        if (m0) b0 = atomicAdd(&tcur[0], __popcll(m0));
        if (m1) b1 = atomicAdd(&tcur[1], __popcll(m1));
        if (m2) b2 = atomicAdd(&tcur[2], __popcll(m2));
    }
    b0 = __shfl(b0, 0); b1 = __shfl(b1, 0); b2 = __shfl(b2, 0);
    if (valid) {
        unsigned long long mk = (t == 0) ? m0 : (t == 1) ? m1 : m2;
        int bs = (t == 0) ? b0 : (t == 1) ? b1 : b2;
        int row = typeoff[t] + bs + __popcll(mk & below);
        noderow[i] = row;
        rowmap[row] = i;
    }
    if (i < N_EDGES) {
        int dst = edst[i];
        int pos = atomicAdd(&cur[dst], 1);
        sorted[pos] = esrc[i] | (etyp[i] << 16);
    }
}

// ---- aggregate: one wave per dst node; gather bf16 x rows, fp32 accum in regs ----
__global__ __launch_bounds__(256) void aggregate(const short* __restrict__ xb,
                                                 const int* __restrict__ offs,
                                                 const int* __restrict__ sorted,
                                                 const int* __restrict__ noderow,
                                                 short* __restrict__ A,
                                                 int* __restrict__ cnt) {
    const int wid = threadIdx.x >> 6, lane = threadIdx.x & 63;
    const int n = blockIdx.x * 4 + wid;
    if (n >= N_NODES) return;
    const int s = offs[n], e = offs[n + 1];
    const int m = e - s;

    float a00=0,a01=0,a02=0,a03=0,a04=0,a05=0,a06=0,a07=0;
    float a10=0,a11=0,a12=0,a13=0,a14=0,a15=0,a16=0,a17=0;
    float a20=0,a21=0,a22=0,a23=0,a24=0,a25=0,a26=0,a27=0;
    int k0 = 0, k1 = 0, k2 = 0;

    int pl = (lane < m) ? sorted[s + lane] : 0;
    const int mm = m < 64 ? m : 64;
    for (int i = 0; i < mm; ++i) {
        int p = __shfl(pl, i);
        int src = p & 0xffff;
        int r = p >> 16;
        uint4 v = ((const uint4*)(xb + (size_t)src * D))[lane];
        float f0 = bflo(v.x), f1 = bfhi(v.x), f2 = bflo(v.y), f3 = bfhi(v.y);
        float f4 = bflo(v.z), f5 = bfhi(v.z), f6 = bflo(v.w), f7 = bfhi(v.w);
        if (r == 0) { a00+=f0;a01+=f1;a02+=f2;a03+=f3;a04+=f4;a05+=f5;a06+=f6;a07+=f7; k0++; }
        else if (r == 1) { a10+=f0;a11+=f1;a12+=f2;a13+=f3;a14+=f4;a15+=f5;a16+=f6;a17+=f7; k1++; }
        else { a20+=f0;a21+=f1;a22+=f2;a23+=f3;a24+=f4;a25+=f5;a26+=f6;a27+=f7; k2++; }
    }
    for (int i = 64; i < m; ++i) {       // overflow path (essentially never taken)
        int p = sorted[s + i];
        int src = p & 0xffff;
        int r = p >> 16;
        uint4 v = ((const uint4*)(xb + (size_t)src * D))[lane];
        float f0 = bflo(v.x), f1 = bfhi(v.x), f2 = bflo(v.y), f3 = bfhi(v.y);
        float f4 = bflo(v.z), f5 = bfhi(v.z), f6 = bflo(v.w), f7 = bfhi(v.w);
        if (r == 0) { a00+=f0;a01+=f1;a02+=f2;a03+=f3;a04+=f4;a05+=f5;a06+=f6;a07+=f7; k0++; }
        else if (r == 1) { a10+=f0;a11+=f1;a12+=f2;a13+=f3;a14+=f4;a15+=f5;a16+=f6;a17+=f7; k1++; }
        else { a20+=f0;a21+=f1;a22+=f2;a23+=f3;a24+=f4;a25+=f5;a26+=f6;a27+=f7; k2++; }
    }

    const int rowid = noderow[n];
    short* row = A + (size_t)rowid * KK;
    uint4 q;
    q.x = pack2(a00, a01); q.y = pack2(a02, a03); q.z = pack2(a04, a05); q.w = pack2(a06, a07);
    *(uint4*)(row + 0 * D + lane * 8) = q;
    q.x = pack2(a10, a11); q.y = pack2(a12, a13); q.z = pack2(a14, a15); q.w = pack2(a16, a17);
    *(uint4*)(row + 1 * D + lane * 8) = q;
    q.x = pack2(a20, a21); q.y = pack2(a22, a23); q.z = pack2(a24, a25); q.w = pack2(a26, a27);
    *(uint4*)(row + 2 * D + lane * 8) = q;
    *(uint4*)(row + 3 * D + lane * 8) = ((const uint4*)(xb + (size_t)n * D))[lane];

    if (lane == 0) {
        cnt[n] = k0;
        cnt[N_NODES + n] = k1;
        cnt[2 * N_NODES + n] = k2;
    }
}

// ---- GEMM: BK=64, swizzled staging (conflict-free), XCD-chunked block map ----
__global__ __launch_bounds__(256, 3) void gemm_bias_relu(
    const short* __restrict__ A, const short* __restrict__ Bt,
    float* __restrict__ out,
    const int* __restrict__ cnt, const float* __restrict__ b_rel,
    const float* __restrict__ b_self, const int* __restrict__ typeoff,
    const int* __restrict__ rowmap) {
    __shared__ short lA[128 * 64];
    __shared__ short lB[128 * 64];
    const int tid = threadIdx.x;
    const int lane = tid & 63;
    const int wid = tid >> 6;
    const int wm = wid >> 1, wn = wid & 1;
    const int lr = lane & 15, lk = lane >> 4;

    // bijective XCD-chunk swizzle: 640 blocks, 8 XCDs, 80/XCD; tn-siblings adjacent
    const int lin = blockIdx.x;
    const int mapped = (lin & 7) * 80 + (lin >> 3);
    const int tm = mapped >> 2;
    const int tn = mapped & 3;

    const int o1 = typeoff[1], o2 = typeoff[2], Mtot = typeoff[3];
    const int arow0 = tm * 128;
    if (arow0 >= Mtot) return;
    const int ttile = (arow0 >= o2) ? 2 : (arow0 >= o1) ? 1 : 0;
    const int tsel = ttile * 512;
    const int brow0 = tn * 128;

    f32x4_t acc[4][4] = {};

    for (int k0 = 0; k0 < KK; k0 += 64) {
        const int bk0 = k0 + (k0 >= KREL ? tsel : 0);
#pragma unroll
        for (int rr = 0; rr < 4; ++rr) {
            int p = rr * 256 + tid;                   // 16B-fragment index 0..1023
            int row = p >> 3;
            int fr = (p & 7) ^ (row & 7);             // source-side swizzle
            GLOAD16(A + (size_t)(arow0 + row) * KK + k0 + fr * 8, ((char*)lA) + p * 16);
            GLOAD16(Bt + (size_t)(brow0 + row) * 3072 + bk0 + fr * 8, ((char*)lB) + p * 16);
        }
        __syncthreads();
#pragma unroll
        for (int ks = 0; ks < 2; ++ks) {
            bf16x8_t af[4], bfr[4];
#pragma unroll
            for (int m = 0; m < 4; ++m) {
                int row_l = wm * 64 + m * 16 + lr;
                int pos = (row_l << 3) + ((ks * 4 + lk) ^ (row_l & 7));
                af[m] = *(const bf16x8_t*)&lA[pos << 3];
            }
#pragma unroll
            for (int n = 0; n < 4; ++n) {
                int row_l = wn * 64 + n * 16 + lr;
                int pos = (row_l << 3) + ((ks * 4 + lk) ^ (row_l & 7));
                bfr[n] = *(const bf16x8_t*)&lB[pos << 3];
            }
#pragma unroll
            for (int m = 0; m < 4; ++m)
#pragma unroll
                for (int n = 0; n < 4; ++n)
                    acc[m][n] = __builtin_amdgcn_mfma_f32_16x16x32_bf16(af[m], bfr[n], acc[m][n], 0, 0, 0);
        }
        __syncthreads();
    }

#pragma unroll
    for (int m = 0; m < 4; ++m) {
#pragma unroll
        for (int q = 0; q < 4; ++q) {
            int rowg = arow0 + wm * 64 + m * 16 + lk * 4 + q;
            int node = rowmap[rowg];
            if (node < 0) continue;
            float c0 = (float)cnt[node];
            float c1 = (float)cnt[N_NODES + node];
            float c2 = (float)cnt[2 * N_NODES + node];
#pragma unroll
            for (int n = 0; n < 4; ++n) {
                int colg = tn * 128 + wn * 64 + n * 16 + lr;
                float v = acc[m][n][q];
                v += c0 * b_rel[colg] + c1 * b_rel[D + colg] + c2 * b_rel[2 * D + colg];
                v += b_self[tsel + colg];
                v = v > 0.f ? v : 0.f;
                out[(size_t)node * D + colg] = v;
            }
        }
    }
}

extern "C" void kernel_launch(void* const* d_in, const int* in_sizes, int n_in,
                              void* d_out, int out_size, void* d_ws, size_t ws_size,
                              hipStream_t stream) {
    const float* x      = (const float*)d_in[0];
    const float* W_rel  = (const float*)d_in[1];
    const float* b_rel  = (const float*)d_in[2];
    const float* W_self = (const float*)d_in[3];
    const float* b_self = (const float*)d_in[4];
    const int* esrc     = (const int*)d_in[5];
    const int* edst     = (const int*)d_in[6];
    const int* etyp     = (const int*)d_in[7];
    const int* ntyp     = (const int*)d_in[8];
    float* out = (float*)d_out;

    char* ws = (char*)d_ws;
    size_t o = 0;
    short* A       = (short*)(ws + o); o += (size_t)NROWS * KK * 2;      // 83,886,080
    short* Bt      = (short*)(ws + o); o += (size_t)D * 3072 * 2;        // 3,145,728
    short* xb      = (short*)(ws + o); o += (size_t)N_NODES * D * 2;     // 20,480,000
    int*   cnt     = (int*)(ws + o);   o += (size_t)3 * N_NODES * 4;     // 240,000
    int*   offs    = (int*)(ws + o);   o += 80032;
    int*   cur     = (int*)(ws + o);   o += 80000;
    int*   noderow = (int*)(ws + o);   o += 80000;
    int*   rowmap  = (int*)(ws + o);   o += (size_t)NROWS * 4;           // 81,920
    int*   sorted  = (int*)(ws + o);   o += 600000;
    // zero-region (cleared by conv_x): hist + tcnt + tcur + typeoff, contiguous
    int*   hist    = (int*)(ws + o);   o += 80000;
    int*   tcnt    = (int*)(ws + o);   o += 16;
    int*   tcur    = (int*)(ws + o);   o += 16;
    int*   typeoff = (int*)(ws + o);   o += 16;

    transpose_B<<<dim3(8, 8, 6), 256, 0, stream>>>(W_rel, W_self, Bt);
    conv_x<<<(N_NODES * D / 8) / 256, 256, 0, stream>>>(x, xb, hist, rowmap);
    count_k<<<(N_EDGES + 255) / 256, 256, 0, stream>>>(edst, hist, ntyp, tcnt);
    scan_k<<<1, 1024, 0, stream>>>(hist, offs, cur, tcnt, typeoff);
    assign_scatter_k<<<(N_EDGES + 255) / 256, 256, 0, stream>>>(
        ntyp, typeoff, tcur, noderow, rowmap, esrc, edst, etyp, cur, sorted);
    aggregate<<<(N_NODES + 3) / 4, 256, 0, stream>>>(xb, offs, sorted, noderow, A, cnt);
    gemm_bias_relu<<<NTILES_M * 4, 256, 0, stream>>>(A, Bt, out, cnt, b_rel, b_self,
                                                     typeoff, rowmap);
}

// Round 5
// 167.073 us; speedup vs baseline: 3.9559x; 1.0214x over previous
//
#include <hip/hip_runtime.h>
#include <hip/hip_bf16.h>

#define N_NODES 20000
#define N_EDGES 150000
#define D 512
#define KK 2048          // GEMM K: 3 rel slots (in A) + 1 self slot (from xb)
#define KREL 1536        // A row stride (3 rel slots only)
#define NROWS 20480      // 320 tiles * 64
#define NTILES_M 320

typedef __attribute__((ext_vector_type(8))) short bf16x8_t;
typedef __attribute__((ext_vector_type(4))) float f32x4_t;

// ---- helpers ----
__device__ __forceinline__ unsigned short f2bf(float x) {
    unsigned u = __float_as_uint(x);
    unsigned r = u + 0x7fffu + ((u >> 16) & 1u);   // RNE
    return (unsigned short)(r >> 16);
}
__device__ __forceinline__ unsigned pack2(float a, float b) {
    return (unsigned)f2bf(a) | ((unsigned)f2bf(b) << 16);
}
__device__ __forceinline__ float bflo(unsigned u) { return __uint_as_float(u << 16); }
__device__ __forceinline__ float bfhi(unsigned u) { return __uint_as_float(u & 0xffff0000u); }

#define GLOAD16(g, l)                                                                   \
    __builtin_amdgcn_global_load_lds(                                                   \
        (const __attribute__((address_space(1))) unsigned*)(g),                         \
        (__attribute__((address_space(3))) unsigned*)(l), 16, 0, 0)

// ---- fused prep: transpose_B (384 blocks) | conv_x (5000) | count (587) ----
#define TB_BLOCKS 384
#define CX_BLOCKS 5000
#define CNT_BLOCKS 587
__global__ __launch_bounds__(256) void fused_prep(
    const float* __restrict__ W_rel, const float* __restrict__ W_self,
    short* __restrict__ Bt,
    const float* __restrict__ x, short* __restrict__ xb,
    const int* __restrict__ edst, int* __restrict__ hist,
    const int* __restrict__ ntype, int* __restrict__ tcnt) {
    __shared__ float tile[64][65];
    const int b = blockIdx.x;
    if (b < TB_BLOCKS) {
        // ---- transpose W into Bt[e][k], row stride 3072 ----
        const int z = b >> 6;                         // 0..5
        const int rem = b & 63;
        const int e0 = (rem & 7) * 64, d0 = (rem >> 3) * 64;
        const float* src = (z < 3) ? (W_rel + (size_t)z * D * D)
                                   : (W_self + (size_t)(z - 3) * D * D);
        const int cbase = (z < 3) ? z * 512 : KREL + (z - 3) * 512;
        const int tx = threadIdx.x & 63, ty = threadIdx.x >> 6;
#pragma unroll
        for (int j = 0; j < 16; ++j) {
            int dl = ty * 16 + j;
            tile[dl][tx] = src[(size_t)(d0 + dl) * D + e0 + tx];
        }
        __syncthreads();
#pragma unroll
        for (int j = 0; j < 16; ++j) {
            int el = ty * 16 + j;
            Bt[(size_t)(e0 + el) * 3072 + cbase + d0 + tx] = (short)f2bf(tile[tx][el]);
        }
    } else if (b < TB_BLOCKS + CX_BLOCKS) {
        // ---- x -> bf16 ----
        int idx = (b - TB_BLOCKS) * 256 + threadIdx.x;   // < 1,280,000
        const float4* s = (const float4*)x + (size_t)idx * 2;
        float4 a = s[0], bb = s[1];
        uint4 pk;
        pk.x = pack2(a.x, a.y);  pk.y = pack2(a.z, a.w);
        pk.z = pack2(bb.x, bb.y); pk.w = pack2(bb.z, bb.w);
        ((uint4*)xb)[idx] = pk;
    } else {
        // ---- edge-dst histogram + node-type counts ----
        int i = (b - TB_BLOCKS - CX_BLOCKS) * 256 + threadIdx.x;
        if (i < N_EDGES) atomicAdd(&hist[edst[i]], 1);
        int lane = threadIdx.x & 63;
        int t = (i < N_NODES) ? ntype[i] : 3;
        unsigned long long m0 = __ballot(t == 0), m1 = __ballot(t == 1), m2 = __ballot(t == 2);
        if (lane == 0) {
            if (m0) atomicAdd(&tcnt[0], __popcll(m0));
            if (m1) atomicAdd(&tcnt[1], __popcll(m1));
            if (m2) atomicAdd(&tcnt[2], __popcll(m2));
        }
    }
}

// ---- scan of 20000 edge-bins -> offs/cur; typeoff; rowmap padding marks ----
__global__ __launch_bounds__(1024) void scan_k(const int* __restrict__ hist,
                                               int* __restrict__ offs,
                                               int* __restrict__ cur,
                                               const int* __restrict__ tcnt,
                                               int* __restrict__ typeoff,
                                               int* __restrict__ rowmap) {
    __shared__ int part[1024];
    const int t = threadIdx.x;
    const int base = t * 20;
    int local[20];
    int sum = 0;
#pragma unroll
    for (int i = 0; i < 20; ++i) {
        int b = base + i;
        int v = (b < N_NODES) ? hist[b] : 0;
        local[i] = sum;
        sum += v;
    }
    part[t] = sum;
    __syncthreads();
    for (int off = 1; off < 1024; off <<= 1) {
        int v = part[t];
        int u = (t >= off) ? part[t - off] : 0;
        __syncthreads();
        part[t] = v + u;
        __syncthreads();
    }
    int tbase = (t > 0) ? part[t - 1] : 0;
#pragma unroll
    for (int i = 0; i < 20; ++i) {
        int b = base + i;
        if (b < N_NODES) {
            int o = tbase + local[i];
            offs[b] = o;
            cur[b] = o;
        }
    }
    if (t == 1023) offs[N_NODES] = part[1023];

    // type offsets (padded to 128) + rowmap = -1 for padding rows only
    int c0 = tcnt[0], c1 = tcnt[1], c2 = tcnt[2];
    int o1 = (c0 + 127) & ~127;
    int o2 = o1 + ((c1 + 127) & ~127);
    int o3 = o2 + ((c2 + 127) & ~127);
    if (t == 0) { typeoff[0] = 0; typeoff[1] = o1; typeoff[2] = o2; typeoff[3] = o3; }
    int p0 = o1 - c0, p1 = o2 - o1 - c1, p2 = o3 - o2 - c2;
    if (t < p0) rowmap[c0 + t] = -1;
    else if (t < p0 + p1) rowmap[o1 + c1 + (t - p0)] = -1;
    else if (t - p0 - p1 < p2) rowmap[o2 + c2 + (t - p0 - p1)] = -1;
}

// ---- node->row assignment (type-grouped) + edge-id scatter (fused) ----
__global__ __launch_bounds__(256) void assign_scatter_k(
    const int* __restrict__ ntype, const int* __restrict__ typeoff,
    int* __restrict__ tcur, int* __restrict__ noderow, int* __restrict__ rowmap,
    const int* __restrict__ esrc, const int* __restrict__ edst,
    const int* __restrict__ etyp, int* __restrict__ cur, int* __restrict__ sorted) {
    int i = blockIdx.x * 256 + threadIdx.x;
    int lane = threadIdx.x & 63;
    bool valid = i < N_NODES;
    int t = valid ? ntype[i] : 3;
    unsigned long long m0 = __ballot(t == 0), m1 = __ballot(t == 1), m2 = __ballot(t == 2);
    unsigned long long below = (lane == 0) ? 0ull : (~0ull >> (64 - lane));
    int b0 = 0, b1 = 0, b2 = 0;
    if (lane == 0) {
        if (m0) b0 = atomicAdd(&tcur[0], __popcll(m0));
        if (m1) b1 = atomicAdd(&tcur[1], __popcll(m1));
        if (m2) b2 = atomicAdd(&tcur[2], __popcll(m2));
    }
    b0 = __shfl(b0, 0); b1 = __shfl(b1, 0); b2 = __shfl(b2, 0);
    if (valid) {
        unsigned long long mk = (t == 0) ? m0 : (t == 1) ? m1 : m2;
        int bs = (t == 0) ? b0 : (t == 1) ? b1 : b2;
        int row = typeoff[t] + bs + __popcll(mk & below);
        noderow[i] = row;
        rowmap[row] = i;
    }
    if (i < N_EDGES) {
        int dst = edst[i];
        int pos = atomicAdd(&cur[dst], 1);
        sorted[pos] = esrc[i] | (etyp[i] << 16);
    }
}

// ---- aggregate: one wave per dst node; 3 rel slots only (stride KREL) ----
__global__ __launch_bounds__(256) void aggregate(const short* __restrict__ xb,
                                                 const int* __restrict__ offs,
                                                 const int* __restrict__ sorted,
                                                 const int* __restrict__ noderow,
                                                 short* __restrict__ A,
                                                 int* __restrict__ cnt) {
    const int wid = threadIdx.x >> 6, lane = threadIdx.x & 63;
    const int n = blockIdx.x * 4 + wid;
    if (n >= N_NODES) return;
    const int s = offs[n], e = offs[n + 1];
    const int m = e - s;

    float a00=0,a01=0,a02=0,a03=0,a04=0,a05=0,a06=0,a07=0;
    float a10=0,a11=0,a12=0,a13=0,a14=0,a15=0,a16=0,a17=0;
    float a20=0,a21=0,a22=0,a23=0,a24=0,a25=0,a26=0,a27=0;
    int k0 = 0, k1 = 0, k2 = 0;

    int pl = (lane < m) ? sorted[s + lane] : 0;
    const int mm = m < 64 ? m : 64;
    for (int i = 0; i < mm; ++i) {
        int p = __shfl(pl, i);
        int src = p & 0xffff;
        int r = p >> 16;
        uint4 v = ((const uint4*)(xb + (size_t)src * D))[lane];
        float f0 = bflo(v.x), f1 = bfhi(v.x), f2 = bflo(v.y), f3 = bfhi(v.y);
        float f4 = bflo(v.z), f5 = bfhi(v.z), f6 = bflo(v.w), f7 = bfhi(v.w);
        if (r == 0) { a00+=f0;a01+=f1;a02+=f2;a03+=f3;a04+=f4;a05+=f5;a06+=f6;a07+=f7; k0++; }
        else if (r == 1) { a10+=f0;a11+=f1;a12+=f2;a13+=f3;a14+=f4;a15+=f5;a16+=f6;a17+=f7; k1++; }
        else { a20+=f0;a21+=f1;a22+=f2;a23+=f3;a24+=f4;a25+=f5;a26+=f6;a27+=f7; k2++; }
    }
    for (int i = 64; i < m; ++i) {       // overflow path (essentially never taken)
        int p = sorted[s + i];
        int src = p & 0xffff;
        int r = p >> 16;
        uint4 v = ((const uint4*)(xb + (size_t)src * D))[lane];
        float f0 = bflo(v.x), f1 = bfhi(v.x), f2 = bflo(v.y), f3 = bfhi(v.y);
        float f4 = bflo(v.z), f5 = bfhi(v.z), f6 = bflo(v.w), f7 = bfhi(v.w);
        if (r == 0) { a00+=f0;a01+=f1;a02+=f2;a03+=f3;a04+=f4;a05+=f5;a06+=f6;a07+=f7; k0++; }
        else if (r == 1) { a10+=f0;a11+=f1;a12+=f2;a13+=f3;a14+=f4;a15+=f5;a16+=f6;a17+=f7; k1++; }
        else { a20+=f0;a21+=f1;a22+=f2;a23+=f3;a24+=f4;a25+=f5;a26+=f6;a27+=f7; k2++; }
    }

    const int rowid = noderow[n];
    short* row = A + (size_t)rowid * KREL;
    uint4 q;
    q.x = pack2(a00, a01); q.y = pack2(a02, a03); q.z = pack2(a04, a05); q.w = pack2(a06, a07);
    *(uint4*)(row + 0 * D + lane * 8) = q;
    q.x = pack2(a10, a11); q.y = pack2(a12, a13); q.z = pack2(a14, a15); q.w = pack2(a16, a17);
    *(uint4*)(row + 1 * D + lane * 8) = q;
    q.x = pack2(a20, a21); q.y = pack2(a22, a23); q.z = pack2(a24, a25); q.w = pack2(a26, a27);
    *(uint4*)(row + 2 * D + lane * 8) = q;

    if (lane == 0) {
        cnt[n] = k0;
        cnt[N_NODES + n] = k1;
        cnt[2 * N_NODES + n] = k2;
    }
}

// ---- GEMM: 64x128 tile, BK=64, self-slot staged from xb, 5 blocks/CU ----
__global__ __launch_bounds__(256, 5) void gemm_bias_relu(
    const short* __restrict__ A, const short* __restrict__ Bt,
    const short* __restrict__ xb, float* __restrict__ out,
    const int* __restrict__ cnt, const float* __restrict__ b_rel,
    const float* __restrict__ b_self, const int* __restrict__ typeoff,
    const int* __restrict__ rowmap) {
    __shared__ short lA[64 * 64];
    __shared__ short lB[128 * 64];
    const int tid = threadIdx.x;
    const int lane = tid & 63;
    const int wid = tid >> 6;
    const int wm = wid >> 1, wn = wid & 1;
    const int lr = lane & 15, lk = lane >> 4;

    // bijective XCD-chunk swizzle: 1280 blocks, 8 XCDs, 160/XCD; tn-siblings adjacent
    const int lin = blockIdx.x;
    const int mapped = (lin & 7) * 160 + (lin >> 3);
    const int tm = mapped >> 2;
    const int tn = mapped & 3;

    const int o1 = typeoff[1], o2 = typeoff[2], Mtot = typeoff[3];
    const int arow0 = tm * 64;
    if (arow0 >= Mtot) return;
    const int ttile = (arow0 >= o2) ? 2 : (arow0 >= o1) ? 1 : 0;
    const int tsel = ttile * 512;
    const int brow0 = tn * 128;

    // staging precompute: 2 A-frags + 4 B-frags per thread, source-side swizzle
    const int rowA0 = tid >> 3;
    const int rowA1 = rowA0 + 32;
    const int frA0 = (tid & 7) ^ (rowA0 & 7);
    const int frA1 = (tid & 7) ^ (rowA1 & 7);
    const int nA0 = rowmap[arow0 + rowA0];
    const int nA1 = rowmap[arow0 + rowA1];
    const short* aA0 = A + (size_t)(arow0 + rowA0) * KREL + frA0 * 8;
    const short* aA1 = A + (size_t)(arow0 + rowA1) * KREL + frA1 * 8;
    const short* xA0 = xb + (size_t)nA0 * D + frA0 * 8;
    const short* xA1 = xb + (size_t)nA1 * D + frA1 * 8;
    char* const ldsA0 = ((char*)lA) + tid * 16;
    char* const ldsA1 = ((char*)lA) + (256 + tid) * 16;
    const int qB0 = tid,        rB0 = qB0 >> 3, fB0 = (qB0 & 7) ^ (rB0 & 7);
    const int qB1 = 256 + tid,  rB1 = qB1 >> 3, fB1 = (qB1 & 7) ^ (rB1 & 7);
    const int qB2 = 512 + tid,  rB2 = qB2 >> 3, fB2 = (qB2 & 7) ^ (rB2 & 7);
    const int qB3 = 768 + tid,  rB3 = qB3 >> 3, fB3 = (qB3 & 7) ^ (rB3 & 7);
    const short* bB0 = Bt + (size_t)(brow0 + rB0) * 3072 + fB0 * 8;
    const short* bB1 = Bt + (size_t)(brow0 + rB1) * 3072 + fB1 * 8;
    const short* bB2 = Bt + (size_t)(brow0 + rB2) * 3072 + fB2 * 8;
    const short* bB3 = Bt + (size_t)(brow0 + rB3) * 3072 + fB3 * 8;
    char* const ldsB0 = ((char*)lB) + qB0 * 16;
    char* const ldsB1 = ((char*)lB) + qB1 * 16;
    char* const ldsB2 = ((char*)lB) + qB2 * 16;
    char* const ldsB3 = ((char*)lB) + qB3 * 16;

    f32x4_t acc[2][4] = {};

    for (int k0 = 0; k0 < KK; k0 += 64) {
        const int bk0 = k0 + (k0 >= KREL ? tsel : 0);
        const short* ga0 = (k0 < KREL) ? (aA0 + k0) : (xA0 + (k0 - KREL));
        const short* ga1 = (k0 < KREL) ? (aA1 + k0) : (xA1 + (k0 - KREL));
        GLOAD16(ga0, ldsA0);
        GLOAD16(ga1, ldsA1);
        GLOAD16(bB0 + bk0, ldsB0);
        GLOAD16(bB1 + bk0, ldsB1);
        GLOAD16(bB2 + bk0, ldsB2);
        GLOAD16(bB3 + bk0, ldsB3);
        __syncthreads();
#pragma unroll
        for (int ks = 0; ks < 2; ++ks) {
            bf16x8_t af[2], bfr[4];
#pragma unroll
            for (int m = 0; m < 2; ++m) {
                int row_l = wm * 32 + m * 16 + lr;
                int pos = (row_l << 3) + ((ks * 4 + lk) ^ (row_l & 7));
                af[m] = *(const bf16x8_t*)&lA[pos << 3];
            }
#pragma unroll
            for (int n = 0; n < 4; ++n) {
                int row_l = wn * 64 + n * 16 + lr;
                int pos = (row_l << 3) + ((ks * 4 + lk) ^ (row_l & 7));
                bfr[n] = *(const bf16x8_t*)&lB[pos << 3];
            }
#pragma unroll
            for (int m = 0; m < 2; ++m)
#pragma unroll
                for (int n = 0; n < 4; ++n)
                    acc[m][n] = __builtin_amdgcn_mfma_f32_16x16x32_bf16(af[m], bfr[n], acc[m][n], 0, 0, 0);
        }
        __syncthreads();
    }

#pragma unroll
    for (int m = 0; m < 2; ++m) {
#pragma unroll
        for (int q = 0; q < 4; ++q) {
            int rowg = arow0 + wm * 32 + m * 16 + lk * 4 + q;
            int node = rowmap[rowg];
            if (node < 0) continue;
            float c0 = (float)cnt[node];
            float c1 = (float)cnt[N_NODES + node];
            float c2 = (float)cnt[2 * N_NODES + node];
#pragma unroll
            for (int n = 0; n < 4; ++n) {
                int colg = tn * 128 + wn * 64 + n * 16 + lr;
                float v = acc[m][n][q];
                v += c0 * b_rel[colg] + c1 * b_rel[D + colg] + c2 * b_rel[2 * D + colg];
                v += b_self[tsel + colg];
                v = v > 0.f ? v : 0.f;
                out[(size_t)node * D + colg] = v;
            }
        }
    }
}

extern "C" void kernel_launch(void* const* d_in, const int* in_sizes, int n_in,
                              void* d_out, int out_size, void* d_ws, size_t ws_size,
                              hipStream_t stream) {
    const float* x      = (const float*)d_in[0];
    const float* W_rel  = (const float*)d_in[1];
    const float* b_rel  = (const float*)d_in[2];
    const float* W_self = (const float*)d_in[3];
    const float* b_self = (const float*)d_in[4];
    const int* esrc     = (const int*)d_in[5];
    const int* edst     = (const int*)d_in[6];
    const int* etyp     = (const int*)d_in[7];
    const int* ntyp     = (const int*)d_in[8];
    float* out = (float*)d_out;

    char* ws = (char*)d_ws;
    size_t o = 0;
    short* A       = (short*)(ws + o); o += (size_t)NROWS * KREL * 2;    // 62,914,560
    short* Bt      = (short*)(ws + o); o += (size_t)D * 3072 * 2;        // 3,145,728
    short* xb      = (short*)(ws + o); o += (size_t)N_NODES * D * 2;     // 20,480,000
    int*   cnt     = (int*)(ws + o);   o += (size_t)3 * N_NODES * 4;     // 240,000
    int*   offs    = (int*)(ws + o);   o += 80032;
    int*   cur     = (int*)(ws + o);   o += 80000;
    int*   noderow = (int*)(ws + o);   o += 80000;
    int*   rowmap  = (int*)(ws + o);   o += (size_t)NROWS * 4;           // 81,920
    int*   sorted  = (int*)(ws + o);   o += 600000;
    // zero-region (memset): hist + tcnt + tcur + typeoff, contiguous 80048 B
    int*   hist    = (int*)(ws + o);   o += 80000;
    int*   tcnt    = (int*)(ws + o);   o += 16;
    int*   tcur    = (int*)(ws + o);   o += 16;
    int*   typeoff = (int*)(ws + o);   o += 16;

    hipMemsetAsync(hist, 0, 80048, stream);
    fused_prep<<<TB_BLOCKS + CX_BLOCKS + CNT_BLOCKS, 256, 0, stream>>>(
        W_rel, W_self, Bt, x, xb, edst, hist, ntyp, tcnt);
    scan_k<<<1, 1024, 0, stream>>>(hist, offs, cur, tcnt, typeoff, rowmap);
    assign_scatter_k<<<(N_EDGES + 255) / 256, 256, 0, stream>>>(
        ntyp, typeoff, tcur, noderow, rowmap, esrc, edst, etyp, cur, sorted);
    aggregate<<<(N_NODES + 3) / 4, 256, 0, stream>>>(xb, offs, sorted, noderow, A, cnt);
    gemm_bias_relu<<<NTILES_M * 4, 256, 0, stream>>>(A, Bt, xb, out, cnt, b_rel, b_self,
                                                     typeoff, rowmap);
}